// Round 12
// baseline (314.851 us; speedup 1.0000x reference)
//
#include <hip/hip_runtime.h>
#include <hip/hip_bf16.h>

// GCN 2-layer on MI355X — global-atomic-free CSR build + register-acc aggregation.
// R5-R15: see git history. agg1 FROZEN at 88us = HW wall (random 128B
//      gathers, 12.8MB table, L2-miss path 3.4 TB/s; 7x reproduced).
// R16-R19: QUARTERING ARC abandoned (L2-resident 32B gathers lose).
// R20: nontemporal store REGRESSED +58us. Reverted.
// R21: pipelined k_gemm, grid 512. 313us.
// R22: k_part LDS-staged counting sort. 302.6us.
// R23: MEASUREMENT: harness ws-poison fill = 42us/iter tops profile;
//      launch+drain boundary ~3-7us each (split cost +20us).
// R24: merged detect+prep, eliminated scanB (scanC recomputes base).
//      9 dispatches, 297.8us.
// R25: collapse CSR build 4 kernels -> 2, NO global scan:
//      k_part2 sorts its 4096 edges by bucket and writes them
//      BLOCK-LOCALLY (contiguous 16KB streams, 1.0x write amplification),
//      publishing per-(bucket,block) local starts (histT) + counts (histC).
//      The rank-returning LDS atomicAdd doubles as the histogram -> k_hist
//      deleted (saves 25.6MB e re-read); scanA/scanC deleted (no global
//      positions needed). k_bstart (196 blocks) row-sums histC ->
//      bucketTotal; each sort2 block derives its global base by reducing
//      <=196 ints. sort2 gathers its bucket's 782 local runs via LDS
//      prefix + 10-step binary search (consecutive k -> coalesced reads).
//      9 -> 7 dispatches. agg1/gemm/agg2/detect_prep byte-identical.
// R26: RESUBMIT of R25 unchanged — R25's bench was an infra failure
//      ("container failed twice", no verdict). Kernel re-audited: bounds,
//      barrier uniformity, search termination, alias ordering all clean.

typedef short s8_t __attribute__((ext_vector_type(8)));
typedef float f4_t __attribute__((ext_vector_type(4)));

__device__ __forceinline__ float bf2f(unsigned short u) {
    union { unsigned int u; float f; } c; c.u = ((unsigned int)u) << 16; return c.f;
}
__device__ __forceinline__ unsigned short f2bf(float f) {
    union { float f; unsigned int u; } c; c.f = f;
    unsigned int u = c.u;
    unsigned int r = (u + 0x7fffu + ((u >> 16) & 1u)) >> 16;  // round-nearest-even
    return (unsigned short)r;
}
__device__ __forceinline__ float loadF(const void* p, int i, int isbf) {
    return isbf ? bf2f(((const unsigned short*)p)[i]) : ((const float*)p)[i];
}
__device__ __forceinline__ int edgeIdx(const void* e, long long i, int is64) {
    return is64 ? (int)((const long long*)e)[i] : ((const int*)e)[i];
}

// Merged detect + weight prep (R24). Wave 0 detects, block preps weights.
__global__ void k_detect_prep(const void* e, const void* x, const void* W1,
                              int* flags, unsigned short* __restrict__ wT,
                              unsigned short* __restrict__ wTh,
                              unsigned short* __restrict__ wTl) {
    __shared__ int sfl;
    int tid = threadIdx.x;   // 256 threads
    if (tid < 64) {
        unsigned int ew = ((const unsigned int*)e)[2 * tid + 1];
        unsigned long long nz = __ballot(ew != 0);
        unsigned int xw = ((const unsigned int*)x)[tid];
        unsigned int low = xw & 0xffffu;
        unsigned int e8 = (low >> 7) & 0xffu;
        bool plaus = (low == 0u) || (e8 >= 110u && e8 <= 135u);
        unsigned long long pl = __ballot(plaus);
        if (tid == 0) {
            flags[0] = (nz == 0ull) ? 1 : 0;
            int isbf = (__popcll(pl) > 32) ? 1 : 0;
            flags[1] = isbf;
            sfl = isbf;
        }
    }
    __syncthreads();
    int isbf = sfl;
    if (isbf) {
        const unsigned short* w = (const unsigned short*)W1;
        for (int idx = tid; idx < 128 * 64; idx += 256) {
            int k = idx >> 6, n = idx & 63;
            wT[n * 128 + k] = w[idx];
        }
    } else {
        const float* w = (const float*)W1;
        for (int idx = tid; idx < 128 * 64; idx += 256) {
            int k = idx >> 6, n = idx & 63;
            float v = w[idx];
            unsigned short h = f2bf(v);
            wTh[n * 128 + k] = h;
            wTl[n * 128 + k] = f2bf(v - bf2f(h));
        }
    }
}

// R25: block-local counting sort of 4096 edges, NO global scan.
// Ranks come from the LDS atomicAdd (hist+rank in one pass). Output is
// block-contiguous: part[block*4096 + slot]. Publishes local starts
// (histT[f*HB+j]) and counts (histC[f*HB+j]) for sort2.
// part value = src | (dstLocal << 17)   (requires N <= 2^17).
__launch_bounds__(256)
__global__ void k_part2(const void* e, int* __restrict__ histT,
                        int* __restrict__ histC, int* __restrict__ part,
                        const int* flags, int E, int B, int HB) {
    __shared__ int lcnt[1024];   // counts -> exclusive local starts (in place)
    __shared__ int sc[256];
    __shared__ int buf[4096];
    int tid = threadIdx.x;
    int is64 = flags[0];
    for (int f = tid; f < 1024; f += 256) lcnt[f] = 0;
    __syncthreads();
    int base = blockIdx.x * 4096;
    int val[16], bk[16], rk[16];
    #pragma unroll
    for (int k = 0; k < 16; ++k) {
        int i = base + k * 256 + tid;
        if (i < E) {
            int s = edgeIdx(e, i, is64);
            int d = edgeIdx(e, (long long)E + i, is64);
            val[k] = s | ((d & 511) << 17);
            bk[k] = d >> 9;
            rk[k] = atomicAdd(&lcnt[bk[k]], 1);   // hist + rank in one op
        } else {
            bk[k] = -1;
        }
    }
    __syncthreads();
    // in-place exclusive scan of lcnt[0..1023] (4 elems/thread + 256-scan)
    int c0 = lcnt[4 * tid], c1 = lcnt[4 * tid + 1];
    int c2 = lcnt[4 * tid + 2], c3 = lcnt[4 * tid + 3];
    int tot = c0 + c1 + c2 + c3;
    sc[tid] = tot; __syncthreads();
    for (int off = 1; off < 256; off <<= 1) {
        int t = (tid >= off) ? sc[tid - off] : 0;
        __syncthreads(); sc[tid] += t; __syncthreads();
    }
    int run = sc[tid] - tot;
    lcnt[4 * tid]     = run;
    lcnt[4 * tid + 1] = run + c0;
    lcnt[4 * tid + 2] = run + c0 + c1;
    lcnt[4 * tid + 3] = run + c0 + c1 + c2;
    __syncthreads();
    // scatter into LDS at local sorted position
    #pragma unroll
    for (int k = 0; k < 16; ++k)
        if (bk[k] >= 0) buf[lcnt[bk[k]] + rk[k]] = val[k];
    __syncthreads();
    // publish local starts + counts (f < B <= 1023, so lcnt[f+1] valid)
    for (int f = tid; f < B; f += 256) {
        int st = lcnt[f], en = lcnt[f + 1];
        histT[(long long)f * HB + blockIdx.x] = st;
        histC[(long long)f * HB + blockIdx.x] = en - st;
    }
    // stream out block-contiguous (perfectly coalesced 16KB)
    int total = E - base; if (total > 4096) total = 4096;
    for (int t = tid; t < total; t += 256) part[base + t] = buf[t];
}

// R25: per-bucket totals = row sum of histC (coalesced row reads).
__launch_bounds__(256)
__global__ void k_bstart(const int* __restrict__ histC,
                         int* __restrict__ bucketTotal, int HB) {
    __shared__ int red[256];
    int tid = threadIdx.x, b = blockIdx.x;
    int s = 0;
    for (int j = tid; j < HB; j += 256) s += histC[(long long)b * HB + j];
    red[tid] = s; __syncthreads();
    for (int off = 128; off > 0; off >>= 1) {
        if (tid < off) red[tid] += red[tid + off];
        __syncthreads();
    }
    if (tid == 0) bucketTotal[b] = red[0];
}

// R25 second sort: block-per-bucket. Gathers the bucket's 782 block-local
// runs via LDS prefix (Pj) + binary search; computes its own global base
// lo = sum(bucketTotal[0..b)). Outputs srcSorted/start/dinv (unchanged
// layout -> agg1/agg2 untouched).
__launch_bounds__(512)
__global__ void k_sort2(const int* __restrict__ part, const int* __restrict__ histT,
                        const int* __restrict__ histC,
                        const int* __restrict__ bucketTotal,
                        int* __restrict__ srcSorted, int* __restrict__ start,
                        float* __restrict__ dinv, int N, int B, int HB, int E) {
    __shared__ int cnt[512];
    __shared__ int s[512];
    __shared__ int cur[512];
    __shared__ int Sj[1024];
    __shared__ int Pj[1024];
    int tid = threadIdx.x, b = blockIdx.x;
    // lo = global start of bucket b = sum of previous bucket totals
    int ls = 0;
    for (int j = tid; j < b; j += 512) ls += bucketTotal[j];
    cnt[tid] = ls; __syncthreads();
    for (int off = 256; off > 0; off >>= 1) {
        if (tid < off) cnt[tid] += cnt[tid + off];
        __syncthreads();
    }
    int lo = cnt[0];
    __syncthreads();
    // load this bucket's rows: Sj = local starts, Pj = counts (then scanned)
    for (int j = tid; j < 1024; j += 512) {
        Sj[j] = (j < HB) ? histT[(long long)b * HB + j] : 0;
        Pj[j] = (j < HB) ? histC[(long long)b * HB + j] : 0;
    }
    __syncthreads();
    // exclusive scan of Pj[0..1023], 2 elems/thread
    int e0 = Pj[2 * tid], e1 = Pj[2 * tid + 1];
    int t2 = e0 + e1;
    s[tid] = t2; __syncthreads();
    for (int off = 1; off < 512; off <<= 1) {
        int t = (tid >= off) ? s[tid - off] : 0;
        __syncthreads(); s[tid] += t; __syncthreads();
    }
    int total = s[511];            // bucket edge count
    int runp = s[tid] - t2;
    Pj[2 * tid] = runp; Pj[2 * tid + 1] = runp + e0;
    cnt[tid] = 0;
    __syncthreads();
    // pass A: histogram dstLocal (binary search run j for each flat k)
    for (int k = tid; k < total; k += 512) {
        int lo2 = 0, hi2 = HB - 1;
        while (lo2 < hi2) {
            int mid = (lo2 + hi2 + 1) >> 1;
            if (Pj[mid] <= k) lo2 = mid; else hi2 = mid - 1;
        }
        int pw = part[lo2 * 4096 + Sj[lo2] + (k - Pj[lo2])];
        atomicAdd(&cnt[(pw >> 17) & 511], 1);
    }
    __syncthreads();
    int v = cnt[tid];
    s[tid] = v; __syncthreads();
    for (int off = 1; off < 512; off <<= 1) {
        int t = (tid >= off) ? s[tid - off] : 0;
        __syncthreads(); s[tid] += t; __syncthreads();
    }
    int base_ = lo + s[tid] - v;   // exclusive-scan position
    cur[tid] = base_;
    int node = b * 512 + tid;
    if (node < N) {
        start[node] = base_;
        dinv[node] = rsqrtf((float)(v + 1));  // +1 self-loop
    }
    if (b == 0 && tid == 0) start[N] = E;
    __syncthreads();
    // pass B: scatter to dst-sorted srcSorted
    for (int k = tid; k < total; k += 512) {
        int lo2 = 0, hi2 = HB - 1;
        while (lo2 < hi2) {
            int mid = (lo2 + hi2 + 1) >> 1;
            if (Pj[mid] <= k) lo2 = mid; else hi2 = mid - 1;
        }
        int pw = part[lo2 * 4096 + Sj[lo2] + (k - Pj[lo2])];
        int pos = atomicAdd(&cur[(pw >> 17) & 511], 1);
        srcSorted[pos] = pw & 0x1FFFF;
    }
}

// Merged MFMA GEMM, LDS-free: hb[row][n] = bf16((x@W1)[row][n] * dinv[row]).
// R21: f32 path software-pipelined across row-blocks. Grid 512.
__launch_bounds__(256)
__global__ void k_gemm(const void* x, const unsigned short* __restrict__ wT,
                       const unsigned short* __restrict__ wTh,
                       const unsigned short* __restrict__ wTl,
                       const float* __restrict__ dinv,
                       unsigned short* __restrict__ hb, const int* flags, int N) {
    int tid = threadIdx.x;
    int lane = tid & 63, wv = tid >> 6;
    int q = lane >> 4, r = lane & 15;
    int gw = blockIdx.x * 4 + wv;
    int nW = gridDim.x * 4;
    int RB = (N + 15) >> 4;
    int isbf = flags[1];
    if (isbf) {
        const unsigned short* xb = (const unsigned short*)x;
        for (int rb = gw; rb < RB; rb += nW) {
            int row0 = rb * 16;
            int arow = row0 + r;
            s8_t a[4];
            #pragma unroll
            for (int kk = 0; kk < 4; ++kk)
                a[kk] = (arow < N)
                    ? *(const s8_t*)&xb[(long long)arow * 128 + kk * 32 + q * 8]
                    : (s8_t)(short)0;
            f4_t acc[4];
            #pragma unroll
            for (int nt = 0; nt < 4; ++nt) acc[nt] = (f4_t){0.f, 0.f, 0.f, 0.f};
            #pragma unroll
            for (int nt = 0; nt < 4; ++nt) {
                #pragma unroll
                for (int kk = 0; kk < 4; ++kk) {
                    s8_t b = *(const s8_t*)&wT[(nt * 16 + r) * 128 + kk * 32 + q * 8];
                    acc[nt] = __builtin_amdgcn_mfma_f32_16x16x32_bf16(a[kk], b, acc[nt], 0, 0, 0);
                }
            }
            #pragma unroll
            for (int reg = 0; reg < 4; ++reg) {
                int row = row0 + q * 4 + reg;
                if (row < N) {
                    float dv = dinv[row];
                    #pragma unroll
                    for (int nt = 0; nt < 4; ++nt)
                        hb[(long long)row * 64 + nt * 16 + r] = f2bf(acc[nt][reg] * dv);
                }
            }
        }
    } else {
        const float* xf = (const float*)x;
        f4_t cx0[4], cx1[4];
        int rb = gw;
        if (rb < RB) {
            int arow = rb * 16 + r;
            #pragma unroll
            for (int kk = 0; kk < 4; ++kk) {
                if (arow < N) {
                    const float* p = &xf[(long long)arow * 128 + kk * 32 + q * 8];
                    cx0[kk] = *(const f4_t*)p;
                    cx1[kk] = *(const f4_t*)(p + 4);
                } else {
                    cx0[kk] = (f4_t){0.f, 0.f, 0.f, 0.f};
                    cx1[kk] = (f4_t){0.f, 0.f, 0.f, 0.f};
                }
            }
        }
        for (; rb < RB; rb += nW) {
            // 1. convert current x to bf16 hi/lo (frees cx for the prefetch)
            s8_t ah[4], al[4];
            #pragma unroll
            for (int kk = 0; kk < 4; ++kk) {
                #pragma unroll
                for (int j = 0; j < 4; ++j) {
                    union { float f; unsigned int u; } c0, h0, r0, c1, h1, r1;
                    c0.f = cx0[kk][j];
                    h0.u = c0.u & 0xffff0000u;
                    ah[kk][j] = (short)(c0.u >> 16);
                    r0.f = c0.f - h0.f;
                    al[kk][j] = (short)(r0.u >> 16);
                    c1.f = cx1[kk][j];
                    h1.u = c1.u & 0xffff0000u;
                    ah[kk][4 + j] = (short)(c1.u >> 16);
                    r1.f = c1.f - h1.f;
                    al[kk][4 + j] = (short)(r1.u >> 16);
                }
            }
            // 2. issue next row-block's loads (fly under the MFMA below)
            int rbn = rb + nW;
            if (rbn < RB) {
                int arow = rbn * 16 + r;
                #pragma unroll
                for (int kk = 0; kk < 4; ++kk) {
                    if (arow < N) {
                        const float* p = &xf[(long long)arow * 128 + kk * 32 + q * 8];
                        cx0[kk] = *(const f4_t*)p;
                        cx1[kk] = *(const f4_t*)(p + 4);
                    } else {
                        cx0[kk] = (f4_t){0.f, 0.f, 0.f, 0.f};
                        cx1[kk] = (f4_t){0.f, 0.f, 0.f, 0.f};
                    }
                }
            }
            // 3. MFMA (wT tables L1/L2-resident)
            f4_t acc[4];
            #pragma unroll
            for (int nt = 0; nt < 4; ++nt) acc[nt] = (f4_t){0.f, 0.f, 0.f, 0.f};
            #pragma unroll
            for (int nt = 0; nt < 4; ++nt) {
                #pragma unroll
                for (int kk = 0; kk < 4; ++kk) {
                    s8_t bh = *(const s8_t*)&wTh[(nt * 16 + r) * 128 + kk * 32 + q * 8];
                    s8_t bl = *(const s8_t*)&wTl[(nt * 16 + r) * 128 + kk * 32 + q * 8];
                    acc[nt] = __builtin_amdgcn_mfma_f32_16x16x32_bf16(ah[kk], bh, acc[nt], 0, 0, 0);
                    acc[nt] = __builtin_amdgcn_mfma_f32_16x16x32_bf16(al[kk], bh, acc[nt], 0, 0, 0);
                    acc[nt] = __builtin_amdgcn_mfma_f32_16x16x32_bf16(ah[kk], bl, acc[nt], 0, 0, 0);
                }
            }
            // 4. store
            int row0 = rb * 16;
            #pragma unroll
            for (int reg = 0; reg < 4; ++reg) {
                int row = row0 + q * 4 + reg;
                if (row < N) {
                    float dv = dinv[row];
                    #pragma unroll
                    for (int nt = 0; nt < 4; ++nt)
                        hb[(long long)row * 64 + nt * 16 + r] = f2bf(acc[nt][reg] * dv);
                }
            }
        }
    }
}

// Layer-1 aggregation + epilogue, wave-per-node, register accumulation.
// R15-exact structure (88us @ 3.4 TB/s = HW wall). FROZEN.
__launch_bounds__(256)
__global__ void k_agg1(const unsigned short* __restrict__ hb,
                       const float* __restrict__ dinv,
                       const int* __restrict__ start,
                       const int* __restrict__ srcSorted,
                       const void* b1, const void* W2, float* __restrict__ sbuf2,
                       const int* flags, int N) {
    int lane = threadIdx.x & 63;
    int node = (blockIdx.x * blockDim.x + threadIdx.x) >> 6;
    if (node >= N) return;
    int isbf = flags[1];
    float di = dinv[node];
    int base = start[node], cnt = start[node + 1] - base;
    float acc = bf2f(hb[(long long)node * 64 + lane]);  // self-loop: *di in epilogue
    for (int c = 0; c < cnt; c += 64) {
        int t = c + lane;
        int sidx = (t < cnt) ? srcSorted[base + t] : 0;
        int m = cnt - c; if (m > 64) m = 64;
        int t2 = 0;
        for (; t2 + 16 <= m; t2 += 16) {
            int s0  = __shfl(sidx, t2 + 0),  s1  = __shfl(sidx, t2 + 1);
            int s2  = __shfl(sidx, t2 + 2),  s3  = __shfl(sidx, t2 + 3);
            int s4  = __shfl(sidx, t2 + 4),  s5  = __shfl(sidx, t2 + 5);
            int s6  = __shfl(sidx, t2 + 6),  s7  = __shfl(sidx, t2 + 7);
            int s8  = __shfl(sidx, t2 + 8),  s9  = __shfl(sidx, t2 + 9);
            int s10 = __shfl(sidx, t2 + 10), s11 = __shfl(sidx, t2 + 11);
            int s12 = __shfl(sidx, t2 + 12), s13 = __shfl(sidx, t2 + 13);
            int s14 = __shfl(sidx, t2 + 14), s15 = __shfl(sidx, t2 + 15);
            unsigned short v0  = hb[(long long)s0  * 64 + lane];
            unsigned short v1  = hb[(long long)s1  * 64 + lane];
            unsigned short v2  = hb[(long long)s2  * 64 + lane];
            unsigned short v3  = hb[(long long)s3  * 64 + lane];
            unsigned short v4  = hb[(long long)s4  * 64 + lane];
            unsigned short v5  = hb[(long long)s5  * 64 + lane];
            unsigned short v6  = hb[(long long)s6  * 64 + lane];
            unsigned short v7  = hb[(long long)s7  * 64 + lane];
            unsigned short v8  = hb[(long long)s8  * 64 + lane];
            unsigned short v9  = hb[(long long)s9  * 64 + lane];
            unsigned short v10 = hb[(long long)s10 * 64 + lane];
            unsigned short v11 = hb[(long long)s11 * 64 + lane];
            unsigned short v12 = hb[(long long)s12 * 64 + lane];
            unsigned short v13 = hb[(long long)s13 * 64 + lane];
            unsigned short v14 = hb[(long long)s14 * 64 + lane];
            unsigned short v15 = hb[(long long)s15 * 64 + lane];
            acc += bf2f(v0);  acc += bf2f(v1);  acc += bf2f(v2);  acc += bf2f(v3);
            acc += bf2f(v4);  acc += bf2f(v5);  acc += bf2f(v6);  acc += bf2f(v7);
            acc += bf2f(v8);  acc += bf2f(v9);  acc += bf2f(v10); acc += bf2f(v11);
            acc += bf2f(v12); acc += bf2f(v13); acc += bf2f(v14); acc += bf2f(v15);
        }
        for (; t2 + 8 <= m; t2 += 8) {
            int s0 = __shfl(sidx, t2 + 0), s1 = __shfl(sidx, t2 + 1);
            int s2 = __shfl(sidx, t2 + 2), s3 = __shfl(sidx, t2 + 3);
            int s4 = __shfl(sidx, t2 + 4), s5 = __shfl(sidx, t2 + 5);
            int s6 = __shfl(sidx, t2 + 6), s7 = __shfl(sidx, t2 + 7);
            unsigned short v0 = hb[(long long)s0 * 64 + lane];
            unsigned short v1 = hb[(long long)s1 * 64 + lane];
            unsigned short v2 = hb[(long long)s2 * 64 + lane];
            unsigned short v3 = hb[(long long)s3 * 64 + lane];
            unsigned short v4 = hb[(long long)s4 * 64 + lane];
            unsigned short v5 = hb[(long long)s5 * 64 + lane];
            unsigned short v6 = hb[(long long)s6 * 64 + lane];
            unsigned short v7 = hb[(long long)s7 * 64 + lane];
            acc += bf2f(v0); acc += bf2f(v1); acc += bf2f(v2); acc += bf2f(v3);
            acc += bf2f(v4); acc += bf2f(v5); acc += bf2f(v6); acc += bf2f(v7);
        }
        for (; t2 < m; ++t2) {
            int s0 = __shfl(sidx, t2);
            acc += bf2f(hb[(long long)s0 * 64 + lane]);
        }
    }
    float v = acc * di + loadF(b1, lane, isbf);
    v = fmaxf(v, 0.f);
    float p = v * loadF(W2, lane, isbf);
    #pragma unroll
    for (int o = 32; o >= 1; o >>= 1) p += __shfl_xor(p, o);
    if (lane == 0) sbuf2[node] = p * di;
}

// Layer-2: out[i] = (sum_src sbuf2[src] + sbuf2[i]) * dinv[i] + b2.
__launch_bounds__(256)
__global__ void k_agg2(const float* __restrict__ sbuf2, const float* __restrict__ dinv,
                       const int* __restrict__ start,
                       const int* __restrict__ srcSorted,
                       const void* b2, void* out, const int* flags, int N) {
    int lane = threadIdx.x & 63;
    int node = (blockIdx.x * blockDim.x + threadIdx.x) >> 6;
    if (node >= N) return;
    int isbf = flags[1];
    float di = dinv[node];
    int base = start[node], cnt = start[node + 1] - base;
    float part = 0.f;
    for (int t = lane; t < cnt; t += 64) part += sbuf2[srcSorted[base + t]];
    #pragma unroll
    for (int o = 32; o >= 1; o >>= 1) part += __shfl_xor(part, o);
    if (lane == 0) {
        float o_ = (part + sbuf2[node]) * di + loadF(b2, 0, isbf);
        if (isbf) ((unsigned short*)out)[node] = f2bf(o_);
        else      ((float*)out)[node] = o_;
    }
}

extern "C" void kernel_launch(void* const* d_in, const int* in_sizes, int n_in,
                              void* d_out, int out_size, void* d_ws, size_t ws_size,
                              hipStream_t stream) {
    const void* x  = d_in[0];
    const void* e  = d_in[1];
    const void* W1 = d_in[2];
    const void* b1 = d_in[3];
    const void* W2 = d_in[4];
    const void* b2 = d_in[5];
    int N = in_sizes[0] / 128;     // 100000
    int E = in_sizes[1] / 2;       // 3200000
    int B  = (N + 511) / 512;      // 196 buckets of 512 nodes
    int HB = (E + 4095) / 4096;    // 782 partition blocks
    int M  = B * HB;               // 153,272
    int Mr = ((M + 255) / 256) * 256;
    int NB = B * 512;              // 100,352 padded nodes
    int EP = ((E + 255) / 256) * 256;

    // Workspace (~28.5 MB; 40.4 MB proven safe, 52.8 MB crashes):
    int*   wsI         = (int*)d_ws;
    int*   flags       = wsI;                              // 256
    unsigned short* wT  = (unsigned short*)(wsI + 256);    // 8192 ushorts (16KB)
    unsigned short* wTh = (unsigned short*)(wsI + 256 + 4096);  // 8192 ushorts
    unsigned short* wTl = (unsigned short*)(wsI + 256 + 8192);  // 8192 ushorts
    int*   histT       = wsI + 256 + 12288;                // Mr ints (local starts)
    int*   histC       = histT + Mr;                       // Mr ints (counts)
    int*   bucketTotal = histC + Mr;                       // 256
    float* dinv        = (float*)(bucketTotal + 256);      // NB
    float* sbuf2       = dinv + NB;                        // NB
    int*   start       = (int*)(sbuf2 + NB);               // NB + 256
    int*   srcSorted   = start + NB + 256;                 // EP
    int*   part        = srcSorted + EP;                   // EP (12.8 MB)
    unsigned short* hb = (unsigned short*)part;            // N*64 bf16, ALIASES part

    hipLaunchKernelGGL(k_detect_prep, dim3(1), dim3(256), 0, stream,
                       e, x, W1, flags, wT, wTh, wTl);
    hipLaunchKernelGGL(k_part2, dim3(HB), dim3(256), 0, stream,
                       e, histT, histC, part, flags, E, B, HB);
    hipLaunchKernelGGL(k_bstart, dim3(B), dim3(256), 0, stream,
                       histC, bucketTotal, HB);
    hipLaunchKernelGGL(k_sort2, dim3(B), dim3(512), 0, stream,
                       part, histT, histC, bucketTotal,
                       srcSorted, start, dinv, N, B, HB, E);
    hipLaunchKernelGGL(k_gemm, dim3(512), dim3(256), 0, stream,
                       x, wT, wTh, wTl, dinv, hb, flags, N);
    hipLaunchKernelGGL(k_agg1, dim3((N + 3) / 4), dim3(256), 0, stream,
                       hb, dinv, start, srcSorted, b1, W2, sbuf2, flags, N);
    hipLaunchKernelGGL(k_agg2, dim3((N + 3) / 4), dim3(256), 0, stream,
                       sbuf2, dinv, start, srcSorted, b2, d_out, flags, N);
}

// Round 13
// 286.243 us; speedup vs baseline: 1.0999x; 1.0999x over previous
//
#include <hip/hip_runtime.h>
#include <hip/hip_bf16.h>

// GCN 2-layer on MI355X — global-atomic-free CSR build + register-acc aggregation.
// R5-R15: see git history. agg1 FROZEN at 88us = HW wall (random 128B
//      gathers, 12.8MB table, L2-miss path 3.4 TB/s; 7x reproduced).
// R16-R19: QUARTERING ARC abandoned (L2-resident 32B gathers lose).
// R20: nontemporal store REGRESSED +58us. Reverted.
// R21: pipelined k_gemm, grid 512. 313us.
// R22: k_part LDS-staged counting sort (stage scatter in LDS, stream out).
// R23: harness ws-poison fill = 42us/iter; launch boundary ~3-7us.
// R24: merged detect+prep, eliminated scanB. 9 dispatches, 297.8us BEST.
// R25/R26: block-local part + binary-search sort2 REGRESSED (+17us):
//      sort2 hit 80us (10-step LDS binary search latency chain, 506K bank
//      conflicts) — BUT measured srcSorted scatter = 95MB WRITE for 12.8MB
//      payload (7.4x amplification), a pattern shared by R24's sort2.
// R27: revert CSR build to R24 exactly; apply the R22 stage-in-LDS pattern
//      to sort2's OUTPUT: pass B scatters into a 96KB dynamic-LDS buffer
//      at bucket-local positions, then streams to srcSorted sequentially
//      (1.0x write amplification). Capacity 24576 >> ~16.4K max bucket;
//      exact fallback to direct scatter if exceeded. Predict sort2 WRITE
//      95->13MB, total ~280-288us.

typedef short s8_t __attribute__((ext_vector_type(8)));
typedef float f4_t __attribute__((ext_vector_type(4)));

__device__ __forceinline__ float bf2f(unsigned short u) {
    union { unsigned int u; float f; } c; c.u = ((unsigned int)u) << 16; return c.f;
}
__device__ __forceinline__ unsigned short f2bf(float f) {
    union { float f; unsigned int u; } c; c.f = f;
    unsigned int u = c.u;
    unsigned int r = (u + 0x7fffu + ((u >> 16) & 1u)) >> 16;  // round-nearest-even
    return (unsigned short)r;
}
__device__ __forceinline__ float loadF(const void* p, int i, int isbf) {
    return isbf ? bf2f(((const unsigned short*)p)[i]) : ((const float*)p)[i];
}
__device__ __forceinline__ int edgeIdx(const void* e, long long i, int is64) {
    return is64 ? (int)((const long long*)e)[i] : ((const int*)e)[i];
}

// Merged detect + weight prep (R24). Wave 0 detects, block preps weights.
__global__ void k_detect_prep(const void* e, const void* x, const void* W1,
                              int* flags, unsigned short* __restrict__ wT,
                              unsigned short* __restrict__ wTh,
                              unsigned short* __restrict__ wTl) {
    __shared__ int sfl;
    int tid = threadIdx.x;   // 256 threads
    if (tid < 64) {
        unsigned int ew = ((const unsigned int*)e)[2 * tid + 1];
        unsigned long long nz = __ballot(ew != 0);
        unsigned int xw = ((const unsigned int*)x)[tid];
        unsigned int low = xw & 0xffffu;
        unsigned int e8 = (low >> 7) & 0xffu;
        bool plaus = (low == 0u) || (e8 >= 110u && e8 <= 135u);
        unsigned long long pl = __ballot(plaus);
        if (tid == 0) {
            flags[0] = (nz == 0ull) ? 1 : 0;
            int isbf = (__popcll(pl) > 32) ? 1 : 0;
            flags[1] = isbf;
            sfl = isbf;
        }
    }
    __syncthreads();
    int isbf = sfl;
    if (isbf) {
        const unsigned short* w = (const unsigned short*)W1;
        for (int idx = tid; idx < 128 * 64; idx += 256) {
            int k = idx >> 6, n = idx & 63;
            wT[n * 128 + k] = w[idx];
        }
    } else {
        const float* w = (const float*)W1;
        for (int idx = tid; idx < 128 * 64; idx += 256) {
            int k = idx >> 6, n = idx & 63;
            float v = w[idx];
            unsigned short h = f2bf(v);
            wTh[n * 128 + k] = h;
            wTl[n * 128 + k] = f2bf(v - bf2f(h));
        }
    }
}

// Per-block LDS histogram over B coarse buckets (dst>>9); hist[bucket][block].
__launch_bounds__(256)
__global__ void k_hist(const void* e, int* __restrict__ histT, const int* flags,
                       int E, int B, int HB) {
    __shared__ int hist[1024];
    int tid = threadIdx.x;
    int is64 = flags[0];
    for (int f = tid; f < B; f += 256) hist[f] = 0;
    __syncthreads();
    int base = blockIdx.x * 4096;
    #pragma unroll
    for (int k = 0; k < 16; ++k) {
        int i = base + k * 256 + tid;
        if (i < E) {
            int d = edgeIdx(e, (long long)E + i, is64);
            atomicAdd(&hist[d >> 9], 1);   // LDS atomic
        }
    }
    __syncthreads();
    for (int f = tid; f < B; f += 256)
        histT[(long long)f * HB + blockIdx.x] = hist[f];
}

// Exclusive scan over M = B*HB ints, level A. partial[b] = block sum (raw).
__global__ void k_scanA(int* __restrict__ data, int* __restrict__ partial, int M) {
    __shared__ int s[256];
    int tid = threadIdx.x;
    int i = blockIdx.x * 256 + tid;
    int v = (i < M) ? data[i] : 0;
    s[tid] = v; __syncthreads();
    for (int off = 1; off < 256; off <<= 1) {
        int t = (tid >= off) ? s[tid - off] : 0;
        __syncthreads(); s[tid] += t; __syncthreads();
    }
    if (i < M) data[i] = s[tid] - v;
    if (tid == 255) partial[blockIdx.x] = s[255];
}

// R24 level C (scanB eliminated): each block recomputes its own base =
// sum(partial[0..bb)) via strided loads + LDS tree reduce (<=599 ints),
// then adds it and extracts bucketStart.
__global__ void k_scanC(int* __restrict__ data, const int* __restrict__ partial,
                        int* __restrict__ bucketStart, int M, int HB, int B, int E) {
    __shared__ int red[256];
    int tid = threadIdx.x;
    int bb = blockIdx.x;
    int s = 0;
    for (int j = tid; j < bb; j += 256) s += partial[j];
    red[tid] = s; __syncthreads();
    for (int off = 128; off > 0; off >>= 1) {
        if (tid < off) red[tid] += red[tid + off];
        __syncthreads();
    }
    int base = red[0];
    int f = bb * 256 + tid;
    if (f < M) {
        int val = data[f] + base;
        data[f] = val;
        int q = f / HB;
        if (f - q * HB == 0) bucketStart[q] = val;
    }
    if (f == 0) bucketStart[B] = E;
}

// Partition (R22): LDS-staged counting sort per block.
// pass1: hist+rank in lcnt; scan lcnt->starts in place; pass2: scatter
// (val,bucket) into LDS; pass3: stream out -> per-bucket CONTIGUOUS runs.
// part[pos] = src | (dstLocal << 17)   (requires N <= 2^17).
__launch_bounds__(256)
__global__ void k_part(const void* e, const int* __restrict__ histT,
                       int* __restrict__ part, const int* flags,
                       int E, int B, int HB) {
    __shared__ int lcur[1024];          // global scanned base per bucket
    __shared__ int lcnt[1024];          // local count -> local start (in place)
    __shared__ int sc[256];             // scan partials
    __shared__ int buf[4096];           // staged edge words
    __shared__ unsigned short bkt[4096];// bucket id per staged slot
    int tid = threadIdx.x;
    int is64 = flags[0];
    for (int f = tid; f < 1024; f += 256) {
        lcur[f] = (f < B) ? histT[(long long)f * HB + blockIdx.x] : 0;
        lcnt[f] = 0;
    }
    __syncthreads();
    int base = blockIdx.x * 4096;
    int val[16], bk[16], rk[16];
    #pragma unroll
    for (int k = 0; k < 16; ++k) {
        int i = base + k * 256 + tid;
        if (i < E) {
            int s = edgeIdx(e, i, is64);
            int d = edgeIdx(e, (long long)E + i, is64);
            val[k] = s | ((d & 511) << 17);
            bk[k] = d >> 9;
            rk[k] = atomicAdd(&lcnt[bk[k]], 1);   // LDS atomic rank
        } else {
            bk[k] = -1;
        }
    }
    __syncthreads();
    // in-place exclusive scan of lcnt[0..1023] (4 elems/thread + 256-scan)
    int c0 = lcnt[4 * tid], c1 = lcnt[4 * tid + 1];
    int c2 = lcnt[4 * tid + 2], c3 = lcnt[4 * tid + 3];
    int tot = c0 + c1 + c2 + c3;
    sc[tid] = tot; __syncthreads();
    for (int off = 1; off < 256; off <<= 1) {
        int t = (tid >= off) ? sc[tid - off] : 0;
        __syncthreads(); sc[tid] += t; __syncthreads();
    }
    int run = sc[tid] - tot;
    lcnt[4 * tid]     = run;
    lcnt[4 * tid + 1] = run + c0;
    lcnt[4 * tid + 2] = run + c0 + c1;
    lcnt[4 * tid + 3] = run + c0 + c1 + c2;
    __syncthreads();
    // pass 2: scatter into LDS at local sorted position
    #pragma unroll
    for (int k = 0; k < 16; ++k) {
        if (bk[k] >= 0) {
            int slot = lcnt[bk[k]] + rk[k];
            buf[slot] = val[k];
            bkt[slot] = (unsigned short)bk[k];
        }
    }
    __syncthreads();
    // pass 3: stream out; consecutive slots in a bucket -> consecutive global
    int total = E - base; if (total > 4096) total = 4096;
    for (int t = tid; t < total; t += 256) {
        int bb = bkt[t];
        part[lcur[bb] + (t - lcnt[bb])] = buf[t];
    }
}

// Block-per-bucket second sort, R27: LDS-staged OUTPUT.
// R26 measured the direct srcSorted scatter at 95MB writes for 12.8MB
// payload (7.4x partial-line amplification). Stage the scatter in a 96KB
// dynamic-LDS buffer at bucket-local positions, then stream out
// sequentially (coalesced, 1.0x). Fallback to direct scatter if a bucket
// exceeds 24576 edges (expected ~16.4K max; never on random data).
__launch_bounds__(512)
__global__ void k_sort2(const int* __restrict__ part, const int* __restrict__ bucketStart,
                        int* __restrict__ srcSorted, int* __restrict__ start,
                        float* __restrict__ dinv, int N, int B) {
    __shared__ int cnt[512];
    __shared__ int s[512];
    __shared__ int cur[512];
    extern __shared__ int sbuf[];   // 24576 ints (96 KB dynamic)
    int tid = threadIdx.x, b = blockIdx.x;
    cnt[tid] = 0;
    __syncthreads();
    int lo = bucketStart[b], hi = bucketStart[b + 1];
    int tot = hi - lo;
    for (int idx = lo + tid; idx < hi; idx += 512)
        atomicAdd(&cnt[(part[idx] >> 17) & 511], 1);
    __syncthreads();
    int v = cnt[tid];
    s[tid] = v; __syncthreads();
    for (int off = 1; off < 512; off <<= 1) {
        int t = (tid >= off) ? s[tid - off] : 0;
        __syncthreads(); s[tid] += t; __syncthreads();
    }
    int loc = s[tid] - v;          // bucket-local exclusive-scan position
    cur[tid] = loc;
    int node = b * 512 + tid;
    if (node < N) {
        start[node] = lo + loc;
        dinv[node] = rsqrtf((float)(v + 1));  // +1 self-loop
    }
    if (b == 0 && tid == 0) start[N] = bucketStart[B];  // = E
    __syncthreads();
    if (tot <= 24576) {
        // scatter into LDS at bucket-local position, stream out coalesced
        for (int idx = lo + tid; idx < hi; idx += 512) {
            int pw = part[idx];
            int pos = atomicAdd(&cur[(pw >> 17) & 511], 1);  // LDS atomic
            sbuf[pos] = pw & 0x1FFFF;
        }
        __syncthreads();
        for (int t = tid; t < tot; t += 512)
            srcSorted[lo + t] = sbuf[t];
    } else {
        // exact fallback: direct global scatter (R24 behavior)
        for (int idx = lo + tid; idx < hi; idx += 512) {
            int pw = part[idx];
            int pos = atomicAdd(&cur[(pw >> 17) & 511], 1);
            srcSorted[lo + pos] = pw & 0x1FFFF;
        }
    }
}

// Merged MFMA GEMM, LDS-free: hb[row][n] = bf16((x@W1)[row][n] * dinv[row]).
// R21: f32 path software-pipelined across row-blocks. Grid 512.
__launch_bounds__(256)
__global__ void k_gemm(const void* x, const unsigned short* __restrict__ wT,
                       const unsigned short* __restrict__ wTh,
                       const unsigned short* __restrict__ wTl,
                       const float* __restrict__ dinv,
                       unsigned short* __restrict__ hb, const int* flags, int N) {
    int tid = threadIdx.x;
    int lane = tid & 63, wv = tid >> 6;
    int q = lane >> 4, r = lane & 15;
    int gw = blockIdx.x * 4 + wv;
    int nW = gridDim.x * 4;
    int RB = (N + 15) >> 4;
    int isbf = flags[1];
    if (isbf) {
        const unsigned short* xb = (const unsigned short*)x;
        for (int rb = gw; rb < RB; rb += nW) {
            int row0 = rb * 16;
            int arow = row0 + r;
            s8_t a[4];
            #pragma unroll
            for (int kk = 0; kk < 4; ++kk)
                a[kk] = (arow < N)
                    ? *(const s8_t*)&xb[(long long)arow * 128 + kk * 32 + q * 8]
                    : (s8_t)(short)0;
            f4_t acc[4];
            #pragma unroll
            for (int nt = 0; nt < 4; ++nt) acc[nt] = (f4_t){0.f, 0.f, 0.f, 0.f};
            #pragma unroll
            for (int nt = 0; nt < 4; ++nt) {
                #pragma unroll
                for (int kk = 0; kk < 4; ++kk) {
                    s8_t b = *(const s8_t*)&wT[(nt * 16 + r) * 128 + kk * 32 + q * 8];
                    acc[nt] = __builtin_amdgcn_mfma_f32_16x16x32_bf16(a[kk], b, acc[nt], 0, 0, 0);
                }
            }
            #pragma unroll
            for (int reg = 0; reg < 4; ++reg) {
                int row = row0 + q * 4 + reg;
                if (row < N) {
                    float dv = dinv[row];
                    #pragma unroll
                    for (int nt = 0; nt < 4; ++nt)
                        hb[(long long)row * 64 + nt * 16 + r] = f2bf(acc[nt][reg] * dv);
                }
            }
        }
    } else {
        const float* xf = (const float*)x;
        f4_t cx0[4], cx1[4];
        int rb = gw;
        if (rb < RB) {
            int arow = rb * 16 + r;
            #pragma unroll
            for (int kk = 0; kk < 4; ++kk) {
                if (arow < N) {
                    const float* p = &xf[(long long)arow * 128 + kk * 32 + q * 8];
                    cx0[kk] = *(const f4_t*)p;
                    cx1[kk] = *(const f4_t*)(p + 4);
                } else {
                    cx0[kk] = (f4_t){0.f, 0.f, 0.f, 0.f};
                    cx1[kk] = (f4_t){0.f, 0.f, 0.f, 0.f};
                }
            }
        }
        for (; rb < RB; rb += nW) {
            // 1. convert current x to bf16 hi/lo (frees cx for the prefetch)
            s8_t ah[4], al[4];
            #pragma unroll
            for (int kk = 0; kk < 4; ++kk) {
                #pragma unroll
                for (int j = 0; j < 4; ++j) {
                    union { float f; unsigned int u; } c0, h0, r0, c1, h1, r1;
                    c0.f = cx0[kk][j];
                    h0.u = c0.u & 0xffff0000u;
                    ah[kk][j] = (short)(c0.u >> 16);
                    r0.f = c0.f - h0.f;
                    al[kk][j] = (short)(r0.u >> 16);
                    c1.f = cx1[kk][j];
                    h1.u = c1.u & 0xffff0000u;
                    ah[kk][4 + j] = (short)(c1.u >> 16);
                    r1.f = c1.f - h1.f;
                    al[kk][4 + j] = (short)(r1.u >> 16);
                }
            }
            // 2. issue next row-block's loads (fly under the MFMA below)
            int rbn = rb + nW;
            if (rbn < RB) {
                int arow = rbn * 16 + r;
                #pragma unroll
                for (int kk = 0; kk < 4; ++kk) {
                    if (arow < N) {
                        const float* p = &xf[(long long)arow * 128 + kk * 32 + q * 8];
                        cx0[kk] = *(const f4_t*)p;
                        cx1[kk] = *(const f4_t*)(p + 4);
                    } else {
                        cx0[kk] = (f4_t){0.f, 0.f, 0.f, 0.f};
                        cx1[kk] = (f4_t){0.f, 0.f, 0.f, 0.f};
                    }
                }
            }
            // 3. MFMA (wT tables L1/L2-resident)
            f4_t acc[4];
            #pragma unroll
            for (int nt = 0; nt < 4; ++nt) acc[nt] = (f4_t){0.f, 0.f, 0.f, 0.f};
            #pragma unroll
            for (int nt = 0; nt < 4; ++nt) {
                #pragma unroll
                for (int kk = 0; kk < 4; ++kk) {
                    s8_t bh = *(const s8_t*)&wTh[(nt * 16 + r) * 128 + kk * 32 + q * 8];
                    s8_t bl = *(const s8_t*)&wTl[(nt * 16 + r) * 128 + kk * 32 + q * 8];
                    acc[nt] = __builtin_amdgcn_mfma_f32_16x16x32_bf16(ah[kk], bh, acc[nt], 0, 0, 0);
                    acc[nt] = __builtin_amdgcn_mfma_f32_16x16x32_bf16(al[kk], bh, acc[nt], 0, 0, 0);
                    acc[nt] = __builtin_amdgcn_mfma_f32_16x16x32_bf16(ah[kk], bl, acc[nt], 0, 0, 0);
                }
            }
            // 4. store
            int row0 = rb * 16;
            #pragma unroll
            for (int reg = 0; reg < 4; ++reg) {
                int row = row0 + q * 4 + reg;
                if (row < N) {
                    float dv = dinv[row];
                    #pragma unroll
                    for (int nt = 0; nt < 4; ++nt)
                        hb[(long long)row * 64 + nt * 16 + r] = f2bf(acc[nt][reg] * dv);
                }
            }
        }
    }
}

// Layer-1 aggregation + epilogue, wave-per-node, register accumulation.
// R15-exact structure (88us @ 3.4 TB/s = HW wall). FROZEN.
__launch_bounds__(256)
__global__ void k_agg1(const unsigned short* __restrict__ hb,
                       const float* __restrict__ dinv,
                       const int* __restrict__ start,
                       const int* __restrict__ srcSorted,
                       const void* b1, const void* W2, float* __restrict__ sbuf2,
                       const int* flags, int N) {
    int lane = threadIdx.x & 63;
    int node = (blockIdx.x * blockDim.x + threadIdx.x) >> 6;
    if (node >= N) return;
    int isbf = flags[1];
    float di = dinv[node];
    int base = start[node], cnt = start[node + 1] - base;
    float acc = bf2f(hb[(long long)node * 64 + lane]);  // self-loop: *di in epilogue
    for (int c = 0; c < cnt; c += 64) {
        int t = c + lane;
        int sidx = (t < cnt) ? srcSorted[base + t] : 0;
        int m = cnt - c; if (m > 64) m = 64;
        int t2 = 0;
        for (; t2 + 16 <= m; t2 += 16) {
            int s0  = __shfl(sidx, t2 + 0),  s1  = __shfl(sidx, t2 + 1);
            int s2  = __shfl(sidx, t2 + 2),  s3  = __shfl(sidx, t2 + 3);
            int s4  = __shfl(sidx, t2 + 4),  s5  = __shfl(sidx, t2 + 5);
            int s6  = __shfl(sidx, t2 + 6),  s7  = __shfl(sidx, t2 + 7);
            int s8  = __shfl(sidx, t2 + 8),  s9  = __shfl(sidx, t2 + 9);
            int s10 = __shfl(sidx, t2 + 10), s11 = __shfl(sidx, t2 + 11);
            int s12 = __shfl(sidx, t2 + 12), s13 = __shfl(sidx, t2 + 13);
            int s14 = __shfl(sidx, t2 + 14), s15 = __shfl(sidx, t2 + 15);
            unsigned short v0  = hb[(long long)s0  * 64 + lane];
            unsigned short v1  = hb[(long long)s1  * 64 + lane];
            unsigned short v2  = hb[(long long)s2  * 64 + lane];
            unsigned short v3  = hb[(long long)s3  * 64 + lane];
            unsigned short v4  = hb[(long long)s4  * 64 + lane];
            unsigned short v5  = hb[(long long)s5  * 64 + lane];
            unsigned short v6  = hb[(long long)s6  * 64 + lane];
            unsigned short v7  = hb[(long long)s7  * 64 + lane];
            unsigned short v8  = hb[(long long)s8  * 64 + lane];
            unsigned short v9  = hb[(long long)s9  * 64 + lane];
            unsigned short v10 = hb[(long long)s10 * 64 + lane];
            unsigned short v11 = hb[(long long)s11 * 64 + lane];
            unsigned short v12 = hb[(long long)s12 * 64 + lane];
            unsigned short v13 = hb[(long long)s13 * 64 + lane];
            unsigned short v14 = hb[(long long)s14 * 64 + lane];
            unsigned short v15 = hb[(long long)s15 * 64 + lane];
            acc += bf2f(v0);  acc += bf2f(v1);  acc += bf2f(v2);  acc += bf2f(v3);
            acc += bf2f(v4);  acc += bf2f(v5);  acc += bf2f(v6);  acc += bf2f(v7);
            acc += bf2f(v8);  acc += bf2f(v9);  acc += bf2f(v10); acc += bf2f(v11);
            acc += bf2f(v12); acc += bf2f(v13); acc += bf2f(v14); acc += bf2f(v15);
        }
        for (; t2 + 8 <= m; t2 += 8) {
            int s0 = __shfl(sidx, t2 + 0), s1 = __shfl(sidx, t2 + 1);
            int s2 = __shfl(sidx, t2 + 2), s3 = __shfl(sidx, t2 + 3);
            int s4 = __shfl(sidx, t2 + 4), s5 = __shfl(sidx, t2 + 5);
            int s6 = __shfl(sidx, t2 + 6), s7 = __shfl(sidx, t2 + 7);
            unsigned short v0 = hb[(long long)s0 * 64 + lane];
            unsigned short v1 = hb[(long long)s1 * 64 + lane];
            unsigned short v2 = hb[(long long)s2 * 64 + lane];
            unsigned short v3 = hb[(long long)s3 * 64 + lane];
            unsigned short v4 = hb[(long long)s4 * 64 + lane];
            unsigned short v5 = hb[(long long)s5 * 64 + lane];
            unsigned short v6 = hb[(long long)s6 * 64 + lane];
            unsigned short v7 = hb[(long long)s7 * 64 + lane];
            acc += bf2f(v0); acc += bf2f(v1); acc += bf2f(v2); acc += bf2f(v3);
            acc += bf2f(v4); acc += bf2f(v5); acc += bf2f(v6); acc += bf2f(v7);
        }
        for (; t2 < m; ++t2) {
            int s0 = __shfl(sidx, t2);
            acc += bf2f(hb[(long long)s0 * 64 + lane]);
        }
    }
    float v = acc * di + loadF(b1, lane, isbf);
    v = fmaxf(v, 0.f);
    float p = v * loadF(W2, lane, isbf);
    #pragma unroll
    for (int o = 32; o >= 1; o >>= 1) p += __shfl_xor(p, o);
    if (lane == 0) sbuf2[node] = p * di;
}

// Layer-2: out[i] = (sum_src sbuf2[src] + sbuf2[i]) * dinv[i] + b2.
__launch_bounds__(256)
__global__ void k_agg2(const float* __restrict__ sbuf2, const float* __restrict__ dinv,
                       const int* __restrict__ start,
                       const int* __restrict__ srcSorted,
                       const void* b2, void* out, const int* flags, int N) {
    int lane = threadIdx.x & 63;
    int node = (blockIdx.x * blockDim.x + threadIdx.x) >> 6;
    if (node >= N) return;
    int isbf = flags[1];
    float di = dinv[node];
    int base = start[node], cnt = start[node + 1] - base;
    float part = 0.f;
    for (int t = lane; t < cnt; t += 64) part += sbuf2[srcSorted[base + t]];
    #pragma unroll
    for (int o = 32; o >= 1; o >>= 1) part += __shfl_xor(part, o);
    if (lane == 0) {
        float o_ = (part + sbuf2[node]) * di + loadF(b2, 0, isbf);
        if (isbf) ((unsigned short*)out)[node] = f2bf(o_);
        else      ((float*)out)[node] = o_;
    }
}

extern "C" void kernel_launch(void* const* d_in, const int* in_sizes, int n_in,
                              void* d_out, int out_size, void* d_ws, size_t ws_size,
                              hipStream_t stream) {
    const void* x  = d_in[0];
    const void* e  = d_in[1];
    const void* W1 = d_in[2];
    const void* b1 = d_in[3];
    const void* W2 = d_in[4];
    const void* b2 = d_in[5];
    int N = in_sizes[0] / 128;     // 100000
    int E = in_sizes[1] / 2;       // 3200000
    int B  = (N + 511) / 512;      // 196 buckets of 512 nodes
    int HB = (E + 4095) / 4096;    // 782 hist blocks
    int M  = B * HB;               // 153,272
    int nP = (M + 255) / 256;      // 599 scanA blocks
    int NB = B * 512;              // 100,352 padded nodes
    int EP = ((E + 255) / 256) * 256;

    // Workspace (~27 MB; 40.4 MB proven safe, 52.8 MB crashes):
    int*   wsI         = (int*)d_ws;
    int*   flags       = wsI;                              // 256
    unsigned short* wT  = (unsigned short*)(wsI + 256);    // 8192 ushorts (16KB)
    unsigned short* wTh = (unsigned short*)(wsI + 256 + 4096);  // 8192 ushorts
    unsigned short* wTl = (unsigned short*)(wsI + 256 + 8192);  // 8192 ushorts
    int*   histT       = wsI + 256 + 12288;                // M rounded
    int*   partial     = histT + ((M + 255) / 256) * 256;  // nP rounded
    int*   bucketStart = partial + ((nP + 255) / 256) * 256;  // B+1 -> 1040
    float* dinv        = (float*)(bucketStart + 1040);     // NB
    float* sbuf2       = dinv + NB;                        // NB
    int*   start       = (int*)(sbuf2 + NB);               // NB + 256
    int*   srcSorted   = start + NB + 256;                 // EP
    int*   part        = srcSorted + EP;                   // EP (12.8 MB)
    unsigned short* hb = (unsigned short*)part;            // N*64 bf16, ALIASES part

    hipLaunchKernelGGL(k_detect_prep, dim3(1), dim3(256), 0, stream,
                       e, x, W1, flags, wT, wTh, wTl);
    hipLaunchKernelGGL(k_hist, dim3(HB), dim3(256), 0, stream, e, histT, flags, E, B, HB);
    hipLaunchKernelGGL(k_scanA, dim3(nP), dim3(256), 0, stream, histT, partial, M);
    hipLaunchKernelGGL(k_scanC, dim3(nP), dim3(256), 0, stream,
                       histT, partial, bucketStart, M, HB, B, E);
    hipLaunchKernelGGL(k_part, dim3(HB), dim3(256), 0, stream, e, histT, part, flags, E, B, HB);
    hipLaunchKernelGGL(k_sort2, dim3(B), dim3(512), 98304, stream,
                       part, bucketStart, srcSorted, start, dinv, N, B);
    hipLaunchKernelGGL(k_gemm, dim3(512), dim3(256), 0, stream,
                       x, wT, wTh, wTl, dinv, hb, flags, N);
    hipLaunchKernelGGL(k_agg1, dim3((N + 3) / 4), dim3(256), 0, stream,
                       hb, dinv, start, srcSorted, b1, W2, sbuf2, flags, N);
    hipLaunchKernelGGL(k_agg2, dim3((N + 3) / 4), dim3(256), 0, stream,
                       sbuf2, dinv, start, srcSorted, b2, d_out, flags, N);
}

// Round 14
// 284.168 us; speedup vs baseline: 1.1080x; 1.0073x over previous
//
#include <hip/hip_runtime.h>
#include <hip/hip_bf16.h>

// GCN 2-layer on MI355X — global-atomic-free CSR build + register-acc aggregation.
// R5-R15: see git history. agg1 FROZEN at 88us = HW wall (random 128B
//      gathers, 12.8MB table, L2-miss path 3.4 TB/s; 8x reproduced).
// R16-R19: QUARTERING ARC abandoned (L2-resident 32B gathers lose).
// R20: nontemporal store REGRESSED +58us. Reverted.
// R21: pipelined k_gemm, grid 512. 313us.
// R22: k_part LDS-staged counting sort (stage scatter in LDS, stream out).
// R23: harness ws-poison fill = 42us/iter; launch boundary ~3-7us.
// R24: merged detect+prep, eliminated scanB. 9 dispatches, 297.8us.
// R25/R26: block-local part + binary-search sort2 REGRESSED; but measured
//      sort2 srcSorted scatter = 95MB writes for 12.8MB payload.
// R27: sort2 output staged in 96KB dynamic LDS, streamed out coalesced
//      (1.0x write amp). 286.2us BEST.
// R28: vectorize CSR-build edge loads (G13: hipcc never auto-vectorizes).
//      k_hist: 16 scalar dst loads/thread -> 4x int4 (4 edges/instr).
//      k_part: 32 scalar src+dst loads/thread -> 8x int4.
//      Both were issue/latency-bound (R5: <10% VALU, low occ; BW floors
//      2us/5us). Edge order within block changes — harmless (ranks only
//      need uniqueness; sums commutative). Tail block keeps scalar path.
//      Everything else byte-identical to R27.

typedef short s8_t __attribute__((ext_vector_type(8)));
typedef float f4_t __attribute__((ext_vector_type(4)));

__device__ __forceinline__ float bf2f(unsigned short u) {
    union { unsigned int u; float f; } c; c.u = ((unsigned int)u) << 16; return c.f;
}
__device__ __forceinline__ unsigned short f2bf(float f) {
    union { float f; unsigned int u; } c; c.f = f;
    unsigned int u = c.u;
    unsigned int r = (u + 0x7fffu + ((u >> 16) & 1u)) >> 16;  // round-nearest-even
    return (unsigned short)r;
}
__device__ __forceinline__ float loadF(const void* p, int i, int isbf) {
    return isbf ? bf2f(((const unsigned short*)p)[i]) : ((const float*)p)[i];
}
__device__ __forceinline__ int edgeIdx(const void* e, long long i, int is64) {
    return is64 ? (int)((const long long*)e)[i] : ((const int*)e)[i];
}
// R28: load 4 consecutive edge indices starting at element i (i % 4 == 0).
__device__ __forceinline__ void edgeIdx4(const void* e, long long i, int is64,
                                         int& v0, int& v1, int& v2, int& v3) {
    if (is64) {
        const int4* p = (const int4*)((const long long*)e + i);
        int4 a = p[0], b = p[1];           // 2 long longs per int4 (LE: low word = .x/.z)
        v0 = a.x; v1 = a.z; v2 = b.x; v3 = b.z;
    } else {
        int4 v = *(const int4*)((const int*)e + i);
        v0 = v.x; v1 = v.y; v2 = v.z; v3 = v.w;
    }
}

// Merged detect + weight prep (R24). Wave 0 detects, block preps weights.
__global__ void k_detect_prep(const void* e, const void* x, const void* W1,
                              int* flags, unsigned short* __restrict__ wT,
                              unsigned short* __restrict__ wTh,
                              unsigned short* __restrict__ wTl) {
    __shared__ int sfl;
    int tid = threadIdx.x;   // 256 threads
    if (tid < 64) {
        unsigned int ew = ((const unsigned int*)e)[2 * tid + 1];
        unsigned long long nz = __ballot(ew != 0);
        unsigned int xw = ((const unsigned int*)x)[tid];
        unsigned int low = xw & 0xffffu;
        unsigned int e8 = (low >> 7) & 0xffu;
        bool plaus = (low == 0u) || (e8 >= 110u && e8 <= 135u);
        unsigned long long pl = __ballot(plaus);
        if (tid == 0) {
            flags[0] = (nz == 0ull) ? 1 : 0;
            int isbf = (__popcll(pl) > 32) ? 1 : 0;
            flags[1] = isbf;
            sfl = isbf;
        }
    }
    __syncthreads();
    int isbf = sfl;
    if (isbf) {
        const unsigned short* w = (const unsigned short*)W1;
        for (int idx = tid; idx < 128 * 64; idx += 256) {
            int k = idx >> 6, n = idx & 63;
            wT[n * 128 + k] = w[idx];
        }
    } else {
        const float* w = (const float*)W1;
        for (int idx = tid; idx < 128 * 64; idx += 256) {
            int k = idx >> 6, n = idx & 63;
            float v = w[idx];
            unsigned short h = f2bf(v);
            wTh[n * 128 + k] = h;
            wTl[n * 128 + k] = f2bf(v - bf2f(h));
        }
    }
}

// Per-block LDS histogram over B coarse buckets (dst>>9); hist[bucket][block].
// R28: int4 dst loads (4 edges/instr) on full blocks.
__launch_bounds__(256)
__global__ void k_hist(const void* e, int* __restrict__ histT, const int* flags,
                       int E, int B, int HB) {
    __shared__ int hist[1024];
    int tid = threadIdx.x;
    int is64 = flags[0];
    for (int f = tid; f < B; f += 256) hist[f] = 0;
    __syncthreads();
    int base = blockIdx.x * 4096;
    if (base + 4096 <= E) {
        #pragma unroll
        for (int k4 = 0; k4 < 4; ++k4) {
            int i = base + (k4 * 256 + tid) * 4;
            int d0, d1, d2, d3;
            edgeIdx4(e, (long long)E + i, is64, d0, d1, d2, d3);
            atomicAdd(&hist[d0 >> 9], 1);
            atomicAdd(&hist[d1 >> 9], 1);
            atomicAdd(&hist[d2 >> 9], 1);
            atomicAdd(&hist[d3 >> 9], 1);
        }
    } else {
        #pragma unroll
        for (int k = 0; k < 16; ++k) {
            int i = base + k * 256 + tid;
            if (i < E) {
                int d = edgeIdx(e, (long long)E + i, is64);
                atomicAdd(&hist[d >> 9], 1);
            }
        }
    }
    __syncthreads();
    for (int f = tid; f < B; f += 256)
        histT[(long long)f * HB + blockIdx.x] = hist[f];
}

// Exclusive scan over M = B*HB ints, level A. partial[b] = block sum (raw).
__global__ void k_scanA(int* __restrict__ data, int* __restrict__ partial, int M) {
    __shared__ int s[256];
    int tid = threadIdx.x;
    int i = blockIdx.x * 256 + tid;
    int v = (i < M) ? data[i] : 0;
    s[tid] = v; __syncthreads();
    for (int off = 1; off < 256; off <<= 1) {
        int t = (tid >= off) ? s[tid - off] : 0;
        __syncthreads(); s[tid] += t; __syncthreads();
    }
    if (i < M) data[i] = s[tid] - v;
    if (tid == 255) partial[blockIdx.x] = s[255];
}

// R24 level C (scanB eliminated): each block recomputes its own base =
// sum(partial[0..bb)) via strided loads + LDS tree reduce (<=599 ints),
// then adds it and extracts bucketStart.
__global__ void k_scanC(int* __restrict__ data, const int* __restrict__ partial,
                        int* __restrict__ bucketStart, int M, int HB, int B, int E) {
    __shared__ int red[256];
    int tid = threadIdx.x;
    int bb = blockIdx.x;
    int s = 0;
    for (int j = tid; j < bb; j += 256) s += partial[j];
    red[tid] = s; __syncthreads();
    for (int off = 128; off > 0; off >>= 1) {
        if (tid < off) red[tid] += red[tid + off];
        __syncthreads();
    }
    int base = red[0];
    int f = bb * 256 + tid;
    if (f < M) {
        int val = data[f] + base;
        data[f] = val;
        int q = f / HB;
        if (f - q * HB == 0) bucketStart[q] = val;
    }
    if (f == 0) bucketStart[B] = E;
}

// Partition (R22): LDS-staged counting sort per block.
// R28: int4 src+dst loads (4 edges / 2 instrs) on full blocks.
// part[pos] = src | (dstLocal << 17)   (requires N <= 2^17).
__launch_bounds__(256)
__global__ void k_part(const void* e, const int* __restrict__ histT,
                       int* __restrict__ part, const int* flags,
                       int E, int B, int HB) {
    __shared__ int lcur[1024];          // global scanned base per bucket
    __shared__ int lcnt[1024];          // local count -> local start (in place)
    __shared__ int sc[256];             // scan partials
    __shared__ int buf[4096];           // staged edge words
    __shared__ unsigned short bkt[4096];// bucket id per staged slot
    int tid = threadIdx.x;
    int is64 = flags[0];
    for (int f = tid; f < 1024; f += 256) {
        lcur[f] = (f < B) ? histT[(long long)f * HB + blockIdx.x] : 0;
        lcnt[f] = 0;
    }
    __syncthreads();
    int base = blockIdx.x * 4096;
    int val[16], bk[16], rk[16];
    if (base + 4096 <= E) {
        #pragma unroll
        for (int k4 = 0; k4 < 4; ++k4) {
            int i = base + (k4 * 256 + tid) * 4;
            int s0, s1, s2, s3, d0, d1, d2, d3;
            edgeIdx4(e, (long long)i, is64, s0, s1, s2, s3);
            edgeIdx4(e, (long long)E + i, is64, d0, d1, d2, d3);
            val[k4 * 4 + 0] = s0 | ((d0 & 511) << 17); bk[k4 * 4 + 0] = d0 >> 9;
            val[k4 * 4 + 1] = s1 | ((d1 & 511) << 17); bk[k4 * 4 + 1] = d1 >> 9;
            val[k4 * 4 + 2] = s2 | ((d2 & 511) << 17); bk[k4 * 4 + 2] = d2 >> 9;
            val[k4 * 4 + 3] = s3 | ((d3 & 511) << 17); bk[k4 * 4 + 3] = d3 >> 9;
            rk[k4 * 4 + 0] = atomicAdd(&lcnt[bk[k4 * 4 + 0]], 1);
            rk[k4 * 4 + 1] = atomicAdd(&lcnt[bk[k4 * 4 + 1]], 1);
            rk[k4 * 4 + 2] = atomicAdd(&lcnt[bk[k4 * 4 + 2]], 1);
            rk[k4 * 4 + 3] = atomicAdd(&lcnt[bk[k4 * 4 + 3]], 1);
        }
    } else {
        #pragma unroll
        for (int k = 0; k < 16; ++k) {
            int i = base + k * 256 + tid;
            if (i < E) {
                int s = edgeIdx(e, i, is64);
                int d = edgeIdx(e, (long long)E + i, is64);
                val[k] = s | ((d & 511) << 17);
                bk[k] = d >> 9;
                rk[k] = atomicAdd(&lcnt[bk[k]], 1);
            } else {
                bk[k] = -1;
            }
        }
    }
    __syncthreads();
    // in-place exclusive scan of lcnt[0..1023] (4 elems/thread + 256-scan)
    int c0 = lcnt[4 * tid], c1 = lcnt[4 * tid + 1];
    int c2 = lcnt[4 * tid + 2], c3 = lcnt[4 * tid + 3];
    int tot = c0 + c1 + c2 + c3;
    sc[tid] = tot; __syncthreads();
    for (int off = 1; off < 256; off <<= 1) {
        int t = (tid >= off) ? sc[tid - off] : 0;
        __syncthreads(); sc[tid] += t; __syncthreads();
    }
    int run = sc[tid] - tot;
    lcnt[4 * tid]     = run;
    lcnt[4 * tid + 1] = run + c0;
    lcnt[4 * tid + 2] = run + c0 + c1;
    lcnt[4 * tid + 3] = run + c0 + c1 + c2;
    __syncthreads();
    // pass 2: scatter into LDS at local sorted position
    #pragma unroll
    for (int k = 0; k < 16; ++k) {
        if (bk[k] >= 0) {
            int slot = lcnt[bk[k]] + rk[k];
            buf[slot] = val[k];
            bkt[slot] = (unsigned short)bk[k];
        }
    }
    __syncthreads();
    // pass 3: stream out; consecutive slots in a bucket -> consecutive global
    int total = E - base; if (total > 4096) total = 4096;
    for (int t = tid; t < total; t += 256) {
        int bb = bkt[t];
        part[lcur[bb] + (t - lcnt[bb])] = buf[t];
    }
}

// Block-per-bucket second sort, R27: LDS-staged OUTPUT (96KB dynamic).
__launch_bounds__(512)
__global__ void k_sort2(const int* __restrict__ part, const int* __restrict__ bucketStart,
                        int* __restrict__ srcSorted, int* __restrict__ start,
                        float* __restrict__ dinv, int N, int B) {
    __shared__ int cnt[512];
    __shared__ int s[512];
    __shared__ int cur[512];
    extern __shared__ int sbuf[];   // 24576 ints (96 KB dynamic)
    int tid = threadIdx.x, b = blockIdx.x;
    cnt[tid] = 0;
    __syncthreads();
    int lo = bucketStart[b], hi = bucketStart[b + 1];
    int tot = hi - lo;
    for (int idx = lo + tid; idx < hi; idx += 512)
        atomicAdd(&cnt[(part[idx] >> 17) & 511], 1);
    __syncthreads();
    int v = cnt[tid];
    s[tid] = v; __syncthreads();
    for (int off = 1; off < 512; off <<= 1) {
        int t = (tid >= off) ? s[tid - off] : 0;
        __syncthreads(); s[tid] += t; __syncthreads();
    }
    int loc = s[tid] - v;          // bucket-local exclusive-scan position
    cur[tid] = loc;
    int node = b * 512 + tid;
    if (node < N) {
        start[node] = lo + loc;
        dinv[node] = rsqrtf((float)(v + 1));  // +1 self-loop
    }
    if (b == 0 && tid == 0) start[N] = bucketStart[B];  // = E
    __syncthreads();
    if (tot <= 24576) {
        for (int idx = lo + tid; idx < hi; idx += 512) {
            int pw = part[idx];
            int pos = atomicAdd(&cur[(pw >> 17) & 511], 1);  // LDS atomic
            sbuf[pos] = pw & 0x1FFFF;
        }
        __syncthreads();
        for (int t = tid; t < tot; t += 512)
            srcSorted[lo + t] = sbuf[t];
    } else {
        for (int idx = lo + tid; idx < hi; idx += 512) {
            int pw = part[idx];
            int pos = atomicAdd(&cur[(pw >> 17) & 511], 1);
            srcSorted[lo + pos] = pw & 0x1FFFF;
        }
    }
}

// Merged MFMA GEMM, LDS-free: hb[row][n] = bf16((x@W1)[row][n] * dinv[row]).
// R21: f32 path software-pipelined across row-blocks. Grid 512.
__launch_bounds__(256)
__global__ void k_gemm(const void* x, const unsigned short* __restrict__ wT,
                       const unsigned short* __restrict__ wTh,
                       const unsigned short* __restrict__ wTl,
                       const float* __restrict__ dinv,
                       unsigned short* __restrict__ hb, const int* flags, int N) {
    int tid = threadIdx.x;
    int lane = tid & 63, wv = tid >> 6;
    int q = lane >> 4, r = lane & 15;
    int gw = blockIdx.x * 4 + wv;
    int nW = gridDim.x * 4;
    int RB = (N + 15) >> 4;
    int isbf = flags[1];
    if (isbf) {
        const unsigned short* xb = (const unsigned short*)x;
        for (int rb = gw; rb < RB; rb += nW) {
            int row0 = rb * 16;
            int arow = row0 + r;
            s8_t a[4];
            #pragma unroll
            for (int kk = 0; kk < 4; ++kk)
                a[kk] = (arow < N)
                    ? *(const s8_t*)&xb[(long long)arow * 128 + kk * 32 + q * 8]
                    : (s8_t)(short)0;
            f4_t acc[4];
            #pragma unroll
            for (int nt = 0; nt < 4; ++nt) acc[nt] = (f4_t){0.f, 0.f, 0.f, 0.f};
            #pragma unroll
            for (int nt = 0; nt < 4; ++nt) {
                #pragma unroll
                for (int kk = 0; kk < 4; ++kk) {
                    s8_t b = *(const s8_t*)&wT[(nt * 16 + r) * 128 + kk * 32 + q * 8];
                    acc[nt] = __builtin_amdgcn_mfma_f32_16x16x32_bf16(a[kk], b, acc[nt], 0, 0, 0);
                }
            }
            #pragma unroll
            for (int reg = 0; reg < 4; ++reg) {
                int row = row0 + q * 4 + reg;
                if (row < N) {
                    float dv = dinv[row];
                    #pragma unroll
                    for (int nt = 0; nt < 4; ++nt)
                        hb[(long long)row * 64 + nt * 16 + r] = f2bf(acc[nt][reg] * dv);
                }
            }
        }
    } else {
        const float* xf = (const float*)x;
        f4_t cx0[4], cx1[4];
        int rb = gw;
        if (rb < RB) {
            int arow = rb * 16 + r;
            #pragma unroll
            for (int kk = 0; kk < 4; ++kk) {
                if (arow < N) {
                    const float* p = &xf[(long long)arow * 128 + kk * 32 + q * 8];
                    cx0[kk] = *(const f4_t*)p;
                    cx1[kk] = *(const f4_t*)(p + 4);
                } else {
                    cx0[kk] = (f4_t){0.f, 0.f, 0.f, 0.f};
                    cx1[kk] = (f4_t){0.f, 0.f, 0.f, 0.f};
                }
            }
        }
        for (; rb < RB; rb += nW) {
            // 1. convert current x to bf16 hi/lo (frees cx for the prefetch)
            s8_t ah[4], al[4];
            #pragma unroll
            for (int kk = 0; kk < 4; ++kk) {
                #pragma unroll
                for (int j = 0; j < 4; ++j) {
                    union { float f; unsigned int u; } c0, h0, r0, c1, h1, r1;
                    c0.f = cx0[kk][j];
                    h0.u = c0.u & 0xffff0000u;
                    ah[kk][j] = (short)(c0.u >> 16);
                    r0.f = c0.f - h0.f;
                    al[kk][j] = (short)(r0.u >> 16);
                    c1.f = cx1[kk][j];
                    h1.u = c1.u & 0xffff0000u;
                    ah[kk][4 + j] = (short)(c1.u >> 16);
                    r1.f = c1.f - h1.f;
                    al[kk][4 + j] = (short)(r1.u >> 16);
                }
            }
            // 2. issue next row-block's loads (fly under the MFMA below)
            int rbn = rb + nW;
            if (rbn < RB) {
                int arow = rbn * 16 + r;
                #pragma unroll
                for (int kk = 0; kk < 4; ++kk) {
                    if (arow < N) {
                        const float* p = &xf[(long long)arow * 128 + kk * 32 + q * 8];
                        cx0[kk] = *(const f4_t*)p;
                        cx1[kk] = *(const f4_t*)(p + 4);
                    } else {
                        cx0[kk] = (f4_t){0.f, 0.f, 0.f, 0.f};
                        cx1[kk] = (f4_t){0.f, 0.f, 0.f, 0.f};
                    }
                }
            }
            // 3. MFMA (wT tables L1/L2-resident)
            f4_t acc[4];
            #pragma unroll
            for (int nt = 0; nt < 4; ++nt) acc[nt] = (f4_t){0.f, 0.f, 0.f, 0.f};
            #pragma unroll
            for (int nt = 0; nt < 4; ++nt) {
                #pragma unroll
                for (int kk = 0; kk < 4; ++kk) {
                    s8_t bh = *(const s8_t*)&wTh[(nt * 16 + r) * 128 + kk * 32 + q * 8];
                    s8_t bl = *(const s8_t*)&wTl[(nt * 16 + r) * 128 + kk * 32 + q * 8];
                    acc[nt] = __builtin_amdgcn_mfma_f32_16x16x32_bf16(ah[kk], bh, acc[nt], 0, 0, 0);
                    acc[nt] = __builtin_amdgcn_mfma_f32_16x16x32_bf16(al[kk], bh, acc[nt], 0, 0, 0);
                    acc[nt] = __builtin_amdgcn_mfma_f32_16x16x32_bf16(ah[kk], bl, acc[nt], 0, 0, 0);
                }
            }
            // 4. store
            int row0 = rb * 16;
            #pragma unroll
            for (int reg = 0; reg < 4; ++reg) {
                int row = row0 + q * 4 + reg;
                if (row < N) {
                    float dv = dinv[row];
                    #pragma unroll
                    for (int nt = 0; nt < 4; ++nt)
                        hb[(long long)row * 64 + nt * 16 + r] = f2bf(acc[nt][reg] * dv);
                }
            }
        }
    }
}

// Layer-1 aggregation + epilogue, wave-per-node, register accumulation.
// R15-exact structure (88us @ 3.4 TB/s = HW wall). FROZEN.
__launch_bounds__(256)
__global__ void k_agg1(const unsigned short* __restrict__ hb,
                       const float* __restrict__ dinv,
                       const int* __restrict__ start,
                       const int* __restrict__ srcSorted,
                       const void* b1, const void* W2, float* __restrict__ sbuf2,
                       const int* flags, int N) {
    int lane = threadIdx.x & 63;
    int node = (blockIdx.x * blockDim.x + threadIdx.x) >> 6;
    if (node >= N) return;
    int isbf = flags[1];
    float di = dinv[node];
    int base = start[node], cnt = start[node + 1] - base;
    float acc = bf2f(hb[(long long)node * 64 + lane]);  // self-loop: *di in epilogue
    for (int c = 0; c < cnt; c += 64) {
        int t = c + lane;
        int sidx = (t < cnt) ? srcSorted[base + t] : 0;
        int m = cnt - c; if (m > 64) m = 64;
        int t2 = 0;
        for (; t2 + 16 <= m; t2 += 16) {
            int s0  = __shfl(sidx, t2 + 0),  s1  = __shfl(sidx, t2 + 1);
            int s2  = __shfl(sidx, t2 + 2),  s3  = __shfl(sidx, t2 + 3);
            int s4  = __shfl(sidx, t2 + 4),  s5  = __shfl(sidx, t2 + 5);
            int s6  = __shfl(sidx, t2 + 6),  s7  = __shfl(sidx, t2 + 7);
            int s8  = __shfl(sidx, t2 + 8),  s9  = __shfl(sidx, t2 + 9);
            int s10 = __shfl(sidx, t2 + 10), s11 = __shfl(sidx, t2 + 11);
            int s12 = __shfl(sidx, t2 + 12), s13 = __shfl(sidx, t2 + 13);
            int s14 = __shfl(sidx, t2 + 14), s15 = __shfl(sidx, t2 + 15);
            unsigned short v0  = hb[(long long)s0  * 64 + lane];
            unsigned short v1  = hb[(long long)s1  * 64 + lane];
            unsigned short v2  = hb[(long long)s2  * 64 + lane];
            unsigned short v3  = hb[(long long)s3  * 64 + lane];
            unsigned short v4  = hb[(long long)s4  * 64 + lane];
            unsigned short v5  = hb[(long long)s5  * 64 + lane];
            unsigned short v6  = hb[(long long)s6  * 64 + lane];
            unsigned short v7  = hb[(long long)s7  * 64 + lane];
            unsigned short v8  = hb[(long long)s8  * 64 + lane];
            unsigned short v9  = hb[(long long)s9  * 64 + lane];
            unsigned short v10 = hb[(long long)s10 * 64 + lane];
            unsigned short v11 = hb[(long long)s11 * 64 + lane];
            unsigned short v12 = hb[(long long)s12 * 64 + lane];
            unsigned short v13 = hb[(long long)s13 * 64 + lane];
            unsigned short v14 = hb[(long long)s14 * 64 + lane];
            unsigned short v15 = hb[(long long)s15 * 64 + lane];
            acc += bf2f(v0);  acc += bf2f(v1);  acc += bf2f(v2);  acc += bf2f(v3);
            acc += bf2f(v4);  acc += bf2f(v5);  acc += bf2f(v6);  acc += bf2f(v7);
            acc += bf2f(v8);  acc += bf2f(v9);  acc += bf2f(v10); acc += bf2f(v11);
            acc += bf2f(v12); acc += bf2f(v13); acc += bf2f(v14); acc += bf2f(v15);
        }
        for (; t2 + 8 <= m; t2 += 8) {
            int s0 = __shfl(sidx, t2 + 0), s1 = __shfl(sidx, t2 + 1);
            int s2 = __shfl(sidx, t2 + 2), s3 = __shfl(sidx, t2 + 3);
            int s4 = __shfl(sidx, t2 + 4), s5 = __shfl(sidx, t2 + 5);
            int s6 = __shfl(sidx, t2 + 6), s7 = __shfl(sidx, t2 + 7);
            unsigned short v0 = hb[(long long)s0 * 64 + lane];
            unsigned short v1 = hb[(long long)s1 * 64 + lane];
            unsigned short v2 = hb[(long long)s2 * 64 + lane];
            unsigned short v3 = hb[(long long)s3 * 64 + lane];
            unsigned short v4 = hb[(long long)s4 * 64 + lane];
            unsigned short v5 = hb[(long long)s5 * 64 + lane];
            unsigned short v6 = hb[(long long)s6 * 64 + lane];
            unsigned short v7 = hb[(long long)s7 * 64 + lane];
            acc += bf2f(v0); acc += bf2f(v1); acc += bf2f(v2); acc += bf2f(v3);
            acc += bf2f(v4); acc += bf2f(v5); acc += bf2f(v6); acc += bf2f(v7);
        }
        for (; t2 < m; ++t2) {
            int s0 = __shfl(sidx, t2);
            acc += bf2f(hb[(long long)s0 * 64 + lane]);
        }
    }
    float v = acc * di + loadF(b1, lane, isbf);
    v = fmaxf(v, 0.f);
    float p = v * loadF(W2, lane, isbf);
    #pragma unroll
    for (int o = 32; o >= 1; o >>= 1) p += __shfl_xor(p, o);
    if (lane == 0) sbuf2[node] = p * di;
}

// Layer-2: out[i] = (sum_src sbuf2[src] + sbuf2[i]) * dinv[i] + b2.
__launch_bounds__(256)
__global__ void k_agg2(const float* __restrict__ sbuf2, const float* __restrict__ dinv,
                       const int* __restrict__ start,
                       const int* __restrict__ srcSorted,
                       const void* b2, void* out, const int* flags, int N) {
    int lane = threadIdx.x & 63;
    int node = (blockIdx.x * blockDim.x + threadIdx.x) >> 6;
    if (node >= N) return;
    int isbf = flags[1];
    float di = dinv[node];
    int base = start[node], cnt = start[node + 1] - base;
    float part = 0.f;
    for (int t = lane; t < cnt; t += 64) part += sbuf2[srcSorted[base + t]];
    #pragma unroll
    for (int o = 32; o >= 1; o >>= 1) part += __shfl_xor(part, o);
    if (lane == 0) {
        float o_ = (part + sbuf2[node]) * di + loadF(b2, 0, isbf);
        if (isbf) ((unsigned short*)out)[node] = f2bf(o_);
        else      ((float*)out)[node] = o_;
    }
}

extern "C" void kernel_launch(void* const* d_in, const int* in_sizes, int n_in,
                              void* d_out, int out_size, void* d_ws, size_t ws_size,
                              hipStream_t stream) {
    const void* x  = d_in[0];
    const void* e  = d_in[1];
    const void* W1 = d_in[2];
    const void* b1 = d_in[3];
    const void* W2 = d_in[4];
    const void* b2 = d_in[5];
    int N = in_sizes[0] / 128;     // 100000
    int E = in_sizes[1] / 2;       // 3200000
    int B  = (N + 511) / 512;      // 196 buckets of 512 nodes
    int HB = (E + 4095) / 4096;    // 782 hist blocks
    int M  = B * HB;               // 153,272
    int nP = (M + 255) / 256;      // 599 scanA blocks
    int NB = B * 512;              // 100,352 padded nodes
    int EP = ((E + 255) / 256) * 256;

    // Workspace (~27 MB; 40.4 MB proven safe, 52.8 MB crashes):
    int*   wsI         = (int*)d_ws;
    int*   flags       = wsI;                              // 256
    unsigned short* wT  = (unsigned short*)(wsI + 256);    // 8192 ushorts (16KB)
    unsigned short* wTh = (unsigned short*)(wsI + 256 + 4096);  // 8192 ushorts
    unsigned short* wTl = (unsigned short*)(wsI + 256 + 8192);  // 8192 ushorts
    int*   histT       = wsI + 256 + 12288;                // M rounded
    int*   partial     = histT + ((M + 255) / 256) * 256;  // nP rounded
    int*   bucketStart = partial + ((nP + 255) / 256) * 256;  // B+1 -> 1040
    float* dinv        = (float*)(bucketStart + 1040);     // NB
    float* sbuf2       = dinv + NB;                        // NB
    int*   start       = (int*)(sbuf2 + NB);               // NB + 256
    int*   srcSorted   = start + NB + 256;                 // EP
    int*   part        = srcSorted + EP;                   // EP (12.8 MB)
    unsigned short* hb = (unsigned short*)part;            // N*64 bf16, ALIASES part

    hipLaunchKernelGGL(k_detect_prep, dim3(1), dim3(256), 0, stream,
                       e, x, W1, flags, wT, wTh, wTl);
    hipLaunchKernelGGL(k_hist, dim3(HB), dim3(256), 0, stream, e, histT, flags, E, B, HB);
    hipLaunchKernelGGL(k_scanA, dim3(nP), dim3(256), 0, stream, histT, partial, M);
    hipLaunchKernelGGL(k_scanC, dim3(nP), dim3(256), 0, stream,
                       histT, partial, bucketStart, M, HB, B, E);
    hipLaunchKernelGGL(k_part, dim3(HB), dim3(256), 0, stream, e, histT, part, flags, E, B, HB);
    hipLaunchKernelGGL(k_sort2, dim3(B), dim3(512), 98304, stream,
                       part, bucketStart, srcSorted, start, dinv, N, B);
    hipLaunchKernelGGL(k_gemm, dim3(512), dim3(256), 0, stream,
                       x, wT, wTh, wTl, dinv, hb, flags, N);
    hipLaunchKernelGGL(k_agg1, dim3((N + 3) / 4), dim3(256), 0, stream,
                       hb, dinv, start, srcSorted, b1, W2, sbuf2, flags, N);
    hipLaunchKernelGGL(k_agg2, dim3((N + 3) / 4), dim3(256), 0, stream,
                       sbuf2, dinv, start, srcSorted, b2, d_out, flags, N);
}